// Round 1
// baseline (584.066 us; speedup 1.0000x reference)
//
#include <hip/hip_runtime.h>

typedef unsigned short u16;
typedef __attribute__((ext_vector_type(8))) short short8;
typedef __attribute__((ext_vector_type(4))) float f32x4;

// Problem dims
#define Bq 4
#define Sq 2048
#define Dq 1024
#define Hq 16
#define HDq 64
#define BSq 8192   // B*S

__device__ __forceinline__ u16 f2bf(float f) {
  unsigned u = __builtin_bit_cast(unsigned, f);
  unsigned r = u + 0x7fffu + ((u >> 16) & 1u);
  return (u16)(r >> 16);
}

// ---------------- fp32 -> bf16 convert (float4 vectorized) ----------------
__global__ void cvt_kernel(const float* __restrict__ in, u16* __restrict__ out, int n4) {
  int i = blockIdx.x * blockDim.x + threadIdx.x;
  if (i >= n4) return;
  float4 v = reinterpret_cast<const float4*>(in)[i];
  ushort4 o;
  o.x = f2bf(v.x); o.y = f2bf(v.y); o.z = f2bf(v.z); o.w = f2bf(v.w);
  reinterpret_cast<ushort4*>(out)[i] = o;
}

// ---------------- transpose + convert: fp32 [R][C] -> bf16 [C][R] ----------------
__global__ void transpose_cvt(const float* __restrict__ in, u16* __restrict__ out, int R, int C) {
  __shared__ float tile[32][33];
  int c0 = blockIdx.x * 32, r0 = blockIdx.y * 32;
  for (int i = threadIdx.y; i < 32; i += 8)
    tile[i][threadIdx.x] = in[(size_t)(r0 + i) * C + c0 + threadIdx.x];
  __syncthreads();
  for (int i = threadIdx.y; i < 32; i += 8)
    out[(size_t)(c0 + i) * R + r0 + threadIdx.x] = f2bf(tile[threadIdx.x][i]);
}

// ---------------- bf16 GEMM: C[M,N] = A[M,K] * Bt[N,K]^T  (+bias) ----------------
// EPI 0: QKV epilogue -> scatter Q (scaled 1/8), K to [B,H,S,HD]; V transposed to [B,H,HD,S]
// EPI 1: proj epilogue -> fp32 Out[M,N] = acc + bias
template<int EPI>
__global__ __launch_bounds__(256)
void gemm_bt(const u16* __restrict__ A, const u16* __restrict__ Bt,
             const float* __restrict__ bias,
             u16* __restrict__ Qb, u16* __restrict__ Kb, u16* __restrict__ Vt,
             float* __restrict__ Out, int Kdim) {
  __shared__ __align__(16) u16 As[128 * 32];
  __shared__ __align__(16) u16 Bs[128 * 32];
  int tid = threadIdx.x;
  int lane = tid & 63, wid = tid >> 6;
  int wr = wid >> 1, wc = wid & 1;       // 2x2 waves; each computes 64x64
  int m0 = blockIdx.y * 128, n0 = blockIdx.x * 128;
  int l15 = lane & 15, g = lane >> 4;
  f32x4 acc[4][4] = {};
  int srow = tid >> 2, scol = (tid & 3) * 8;

  for (int k0 = 0; k0 < Kdim; k0 += 32) {
    short8 a0 = *reinterpret_cast<const short8*>(&A[(size_t)(m0 + srow) * Kdim + k0 + scol]);
    short8 a1 = *reinterpret_cast<const short8*>(&A[(size_t)(m0 + 64 + srow) * Kdim + k0 + scol]);
    short8 b0 = *reinterpret_cast<const short8*>(&Bt[(size_t)(n0 + srow) * Kdim + k0 + scol]);
    short8 b1 = *reinterpret_cast<const short8*>(&Bt[(size_t)(n0 + 64 + srow) * Kdim + k0 + scol]);
    __syncthreads();
    *reinterpret_cast<short8*>(&As[srow * 32 + scol]) = a0;
    *reinterpret_cast<short8*>(&As[(64 + srow) * 32 + scol]) = a1;
    *reinterpret_cast<short8*>(&Bs[srow * 32 + scol]) = b0;
    *reinterpret_cast<short8*>(&Bs[(64 + srow) * 32 + scol]) = b1;
    __syncthreads();
    short8 af[4], bfr[4];
#pragma unroll
    for (int m = 0; m < 4; ++m)
      af[m] = *reinterpret_cast<const short8*>(&As[(wr * 64 + m * 16 + l15) * 32 + g * 8]);
#pragma unroll
    for (int n = 0; n < 4; ++n)
      bfr[n] = *reinterpret_cast<const short8*>(&Bs[(wc * 64 + n * 16 + l15) * 32 + g * 8]);
#pragma unroll
    for (int m = 0; m < 4; ++m)
#pragma unroll
      for (int n = 0; n < 4; ++n)
        acc[m][n] = __builtin_amdgcn_mfma_f32_16x16x32_bf16(af[m], bfr[n], acc[m][n], 0, 0, 0);
  }

#pragma unroll
  for (int m = 0; m < 4; ++m) {
#pragma unroll
    for (int n = 0; n < 4; ++n) {
      int gcol = n0 + wc * 64 + n * 16 + l15;
      float bv = bias[gcol];
#pragma unroll
      for (int r = 0; r < 4; ++r) {
        int grow = m0 + wr * 64 + m * 16 + g * 4 + r;
        float v = acc[m][n][r] + bv;
        if (EPI == 0) {
          int b = grow >> 11, s = grow & 2047;
          if (gcol < 1024) {
            int h = gcol >> 6, d = gcol & 63;
            Qb[(((size_t)(b * 16 + h) * 2048 + s) << 6) + d] = f2bf(v * 0.125f);
          } else if (gcol < 2048) {
            int c = gcol - 1024, h = c >> 6, d = c & 63;
            Kb[(((size_t)(b * 16 + h) * 2048 + s) << 6) + d] = f2bf(v);
          } else {
            int c = gcol - 2048, h = c >> 6, d = c & 63;
            Vt[((size_t)(b * 16 + h) * 64 + d) * 2048 + s] = f2bf(v);
          }
        } else {
          Out[(size_t)grow * 1024 + gcol] = v;
        }
      }
    }
  }
}

// ---------------- flash attention (causal), bf16 MFMA ----------------
// grid: (S/64 q-blocks, B*H). 4 waves; wave w owns 16 q rows.
__global__ __launch_bounds__(256)
void attn_kernel(const u16* __restrict__ Qb, const u16* __restrict__ Kb,
                 const u16* __restrict__ Vt, u16* __restrict__ Ctx) {
  __shared__ __align__(16) u16 P[4][16 * 32];
  int tid = threadIdx.x, lane = tid & 63, wid = tid >> 6;
  int l15 = lane & 15, g = lane >> 4;
  int qb = blockIdx.x, bh = blockIdx.y;
  int q0 = qb * 64 + wid * 16;
  const u16* Qh = Qb + (size_t)bh * Sq * HDq;
  const u16* Kh = Kb + (size_t)bh * Sq * HDq;
  const u16* Vh = Vt + (size_t)bh * HDq * Sq;

  short8 qf[2];
  qf[0] = *reinterpret_cast<const short8*>(&Qh[(q0 + l15) * 64 + g * 8]);
  qf[1] = *reinterpret_cast<const short8*>(&Qh[(q0 + l15) * 64 + 32 + g * 8]);

  f32x4 acc[4] = {};
  float m_r[4] = {-INFINITY, -INFINITY, -INFINITY, -INFINITY};
  float l_r[4] = {0.f, 0.f, 0.f, 0.f};
  int rowBase = q0 + g * 4;
  int nkb = 2 * qb + 2;  // K-blocks of 32 covering cols 0..qb*64+63

  for (int kb = 0; kb < nkb; ++kb) {
    int k0 = kb * 32;
    f32x4 s0 = {}, s1 = {};
#pragma unroll
    for (int h = 0; h < 2; ++h) {
      short8 kf0 = *reinterpret_cast<const short8*>(&Kh[(k0 + l15) * 64 + h * 32 + g * 8]);
      short8 kf1 = *reinterpret_cast<const short8*>(&Kh[(k0 + 16 + l15) * 64 + h * 32 + g * 8]);
      s0 = __builtin_amdgcn_mfma_f32_16x16x32_bf16(qf[h], kf0, s0, 0, 0, 0);
      s1 = __builtin_amdgcn_mfma_f32_16x16x32_bf16(qf[h], kf1, s1, 0, 0, 0);
    }
    if (k0 + 31 > q0) {  // partial / masked block: apply causal mask
#pragma unroll
      for (int r = 0; r < 4; ++r) {
        int row = rowBase + r;
        if (k0 + l15 > row) s0[r] = -1e30f;
        if (k0 + 16 + l15 > row) s1[r] = -1e30f;
      }
    }
    float tm[4], p0[4], p1[4], rs[4], scn[4];
#pragma unroll
    for (int r = 0; r < 4; ++r) tm[r] = fmaxf(s0[r], s1[r]);
#pragma unroll
    for (int off = 1; off < 16; off <<= 1)
#pragma unroll
      for (int r = 0; r < 4; ++r) tm[r] = fmaxf(tm[r], __shfl_xor(tm[r], off));
#pragma unroll
    for (int r = 0; r < 4; ++r) {
      float mn = fmaxf(m_r[r], tm[r]);
      scn[r] = __expf(m_r[r] - mn);
      p0[r] = __expf(s0[r] - mn);
      p1[r] = __expf(s1[r] - mn);
      rs[r] = p0[r] + p1[r];
      m_r[r] = mn;
    }
#pragma unroll
    for (int off = 1; off < 16; off <<= 1)
#pragma unroll
      for (int r = 0; r < 4; ++r) rs[r] += __shfl_xor(rs[r], off);
#pragma unroll
    for (int r = 0; r < 4; ++r) l_r[r] = l_r[r] * scn[r] + rs[r];
#pragma unroll
    for (int n = 0; n < 4; ++n)
#pragma unroll
      for (int r = 0; r < 4; ++r) acc[n][r] *= scn[r];
    // write P tile (16x32) to per-wave LDS in A-operand-friendly row-major
#pragma unroll
    for (int r = 0; r < 4; ++r) {
      P[wid][(g * 4 + r) * 32 + l15] = f2bf(p0[r]);
      P[wid][(g * 4 + r) * 32 + 16 + l15] = f2bf(p1[r]);
    }
    __syncthreads();
    short8 pa = *reinterpret_cast<const short8*>(&P[wid][l15 * 32 + g * 8]);
#pragma unroll
    for (int n = 0; n < 4; ++n) {
      short8 vb = *reinterpret_cast<const short8*>(&Vh[(size_t)(n * 16 + l15) * Sq + k0 + g * 8]);
      acc[n] = __builtin_amdgcn_mfma_f32_16x16x32_bf16(pa, vb, acc[n], 0, 0, 0);
    }
    __syncthreads();
  }

  int b = bh >> 4, h = bh & 15;
#pragma unroll
  for (int r = 0; r < 4; ++r) {
    float inv = 1.0f / l_r[r];
    int row = rowBase + r;
    size_t base = ((size_t)(b * Sq + row)) * Dq + h * 64;
#pragma unroll
    for (int n = 0; n < 4; ++n)
      Ctx[base + n * 16 + l15] = f2bf(acc[n][r] * inv);
  }
}

extern "C" void kernel_launch(void* const* d_in, const int* in_sizes, int n_in,
                              void* d_out, int out_size, void* d_ws, size_t ws_size,
                              hipStream_t stream) {
  const float* X  = (const float*)d_in[0];   // [B,S,D] fp32
  const float* Wa = (const float*)d_in[1];   // [D,3D]
  const float* Ba = (const float*)d_in[2];   // [3D]
  const float* Wp = (const float*)d_in[3];   // [D,D]
  const float* Bp = (const float*)d_in[4];   // [D]
  float* Out = (float*)d_out;                // [B,S,D] fp32

  u16* ws  = (u16*)d_ws;
  u16* Xb  = ws;                                 // 8192*1024
  u16* WaT = Xb  + (size_t)BSq * Dq;             // 3072*1024
  u16* WpT = WaT + (size_t)3 * Dq * Dq;          // 1024*1024
  u16* Qb  = WpT + (size_t)Dq * Dq;              // 64*2048*64
  u16* Kb  = Qb  + (size_t)Bq * Hq * Sq * HDq;
  u16* Vt  = Kb  + (size_t)Bq * Hq * Sq * HDq;
  u16* Ctx = Vt  + (size_t)Bq * Hq * Sq * HDq;   // 8192*1024

  // 1) convert X to bf16
  cvt_kernel<<<(BSq * Dq / 4 + 255) / 256, 256, 0, stream>>>(X, Xb, BSq * Dq / 4);
  // 2) transpose+convert weights: W[K][N] -> WT[N][K] bf16
  transpose_cvt<<<dim3(3 * Dq / 32, Dq / 32), dim3(32, 8), 0, stream>>>(Wa, WaT, Dq, 3 * Dq);
  transpose_cvt<<<dim3(Dq / 32, Dq / 32), dim3(32, 8), 0, stream>>>(Wp, WpT, Dq, Dq);
  // 3) QKV GEMM (M=8192, N=3072, K=1024) with Q/K/V scatter epilogue
  gemm_bt<0><<<dim3(3 * Dq / 128, BSq / 128), 256, 0, stream>>>(Xb, WaT, Ba, Qb, Kb, Vt, nullptr, Dq);
  // 4) causal flash attention -> Ctx [B,S,H*HD] bf16
  attn_kernel<<<dim3(Sq / 64, Bq * Hq), 256, 0, stream>>>(Qb, Kb, Vt, Ctx);
  // 5) output projection (M=8192, N=1024, K=1024) -> fp32 out
  gemm_bt<1><<<dim3(Dq / 128, BSq / 128), 256, 0, stream>>>(Ctx, WpT, Bp, nullptr, nullptr, nullptr, Out, Dq);
}

// Round 2
// 367.010 us; speedup vs baseline: 1.5914x; 1.5914x over previous
//
#include <hip/hip_runtime.h>

typedef unsigned short u16;
typedef __attribute__((ext_vector_type(8))) short short8;
typedef __attribute__((ext_vector_type(4))) float f32x4;

// Problem dims
#define Bq 4
#define Sq 2048
#define Dq 1024
#define Hq 16
#define HDq 64
#define BSq 8192   // B*S

// Q pre-scale: 1/sqrt(64) * log2(e)  (softmax done in exp2 domain)
#define QSCALE 0.18033688011112042f

__device__ __forceinline__ u16 f2bf(float f) {
  unsigned u = __builtin_bit_cast(unsigned, f);
  unsigned r = u + 0x7fffu + ((u >> 16) & 1u);
  return (u16)(r >> 16);
}

// k-permutation for V^T storage: kk = 16j + 4g + r  ->  k' = (j&1)<<5 | g<<3 | (j>>1)<<2 | r
__device__ __forceinline__ int kperm(int kk) {
  return ((kk & 0x10) << 1) | ((kk & 0x0C) << 1) | ((kk & 0x20) >> 3) | (kk & 3);
}

// ---------------- fp32 -> bf16 convert (float4 vectorized) ----------------
__global__ void cvt_kernel(const float* __restrict__ in, u16* __restrict__ out, int n4) {
  int i = blockIdx.x * blockDim.x + threadIdx.x;
  if (i >= n4) return;
  float4 v = reinterpret_cast<const float4*>(in)[i];
  ushort4 o;
  o.x = f2bf(v.x); o.y = f2bf(v.y); o.z = f2bf(v.z); o.w = f2bf(v.w);
  reinterpret_cast<ushort4*>(out)[i] = o;
}

// ---------------- transpose + convert: fp32 [R][C] -> bf16 [C][R] ----------------
__global__ void transpose_cvt(const float* __restrict__ in, u16* __restrict__ out, int R, int C) {
  __shared__ float tile[32][33];
  int c0 = blockIdx.x * 32, r0 = blockIdx.y * 32;
  for (int i = threadIdx.y; i < 32; i += 8)
    tile[i][threadIdx.x] = in[(size_t)(r0 + i) * C + c0 + threadIdx.x];
  __syncthreads();
  for (int i = threadIdx.y; i < 32; i += 8)
    out[(size_t)(c0 + i) * R + r0 + threadIdx.x] = f2bf(tile[threadIdx.x][i]);
}

// ---------------- bf16 GEMM: C[M,N] = A[M,K] * Bt[N,K]^T  (+bias) ----------------
// EPI 0: QKV epilogue -> Q (scaled QSCALE), K to [B,H,S,HD]; V transposed+k-permuted to [B,H,HD,S]
// EPI 1: proj epilogue -> fp32 Out[M,N] = acc + bias
template<int EPI>
__global__ __launch_bounds__(256)
void gemm_bt(const u16* __restrict__ A, const u16* __restrict__ Bt,
             const float* __restrict__ bias,
             u16* __restrict__ Qb, u16* __restrict__ Kb, u16* __restrict__ Vt,
             float* __restrict__ Out, int Kdim) {
  __shared__ __align__(16) u16 As[128 * 32];
  __shared__ __align__(16) u16 Bs[128 * 32];
  int tid = threadIdx.x;
  int lane = tid & 63, wid = tid >> 6;
  int wr = wid >> 1, wc = wid & 1;       // 2x2 waves; each computes 64x64
  int m0 = blockIdx.y * 128, n0 = blockIdx.x * 128;
  int l15 = lane & 15, g = lane >> 4;
  f32x4 acc[4][4] = {};
  int srow = tid >> 2, scol = (tid & 3) * 8;

  for (int k0 = 0; k0 < Kdim; k0 += 32) {
    short8 a0 = *reinterpret_cast<const short8*>(&A[(size_t)(m0 + srow) * Kdim + k0 + scol]);
    short8 a1 = *reinterpret_cast<const short8*>(&A[(size_t)(m0 + 64 + srow) * Kdim + k0 + scol]);
    short8 b0 = *reinterpret_cast<const short8*>(&Bt[(size_t)(n0 + srow) * Kdim + k0 + scol]);
    short8 b1 = *reinterpret_cast<const short8*>(&Bt[(size_t)(n0 + 64 + srow) * Kdim + k0 + scol]);
    __syncthreads();
    *reinterpret_cast<short8*>(&As[srow * 32 + scol]) = a0;
    *reinterpret_cast<short8*>(&As[(64 + srow) * 32 + scol]) = a1;
    *reinterpret_cast<short8*>(&Bs[srow * 32 + scol]) = b0;
    *reinterpret_cast<short8*>(&Bs[(64 + srow) * 32 + scol]) = b1;
    __syncthreads();
    short8 af[4], bfr[4];
#pragma unroll
    for (int m = 0; m < 4; ++m)
      af[m] = *reinterpret_cast<const short8*>(&As[(wr * 64 + m * 16 + l15) * 32 + g * 8]);
#pragma unroll
    for (int n = 0; n < 4; ++n)
      bfr[n] = *reinterpret_cast<const short8*>(&Bs[(wc * 64 + n * 16 + l15) * 32 + g * 8]);
#pragma unroll
    for (int m = 0; m < 4; ++m)
#pragma unroll
      for (int n = 0; n < 4; ++n)
        acc[m][n] = __builtin_amdgcn_mfma_f32_16x16x32_bf16(af[m], bfr[n], acc[m][n], 0, 0, 0);
  }

#pragma unroll
  for (int m = 0; m < 4; ++m) {
#pragma unroll
    for (int n = 0; n < 4; ++n) {
      int gcol = n0 + wc * 64 + n * 16 + l15;
      float bv = bias[gcol];
#pragma unroll
      for (int r = 0; r < 4; ++r) {
        int grow = m0 + wr * 64 + m * 16 + g * 4 + r;
        float v = acc[m][n][r] + bv;
        if (EPI == 0) {
          int b = grow >> 11, s = grow & 2047;
          if (gcol < 1024) {
            int h = gcol >> 6, d = gcol & 63;
            Qb[(((size_t)(b * 16 + h) * 2048 + s) << 6) + d] = f2bf(v * QSCALE);
          } else if (gcol < 2048) {
            int c = gcol - 1024, h = c >> 6, d = c & 63;
            Kb[(((size_t)(b * 16 + h) * 2048 + s) << 6) + d] = f2bf(v);
          } else {
            int c = gcol - 2048, h = c >> 6, d = c & 63;
            Vt[((size_t)(b * 16 + h) * 64 + d) * 2048 + (s & ~63) + kperm(s & 63)] = f2bf(v);
          }
        } else {
          Out[(size_t)grow * 1024 + gcol] = v;
        }
      }
    }
  }
}

// ---------------- flash attention (causal), swapped-QK^T, all-register P ----------------
// grid: (S/128 q-tiles, B*H). 4 waves; wave w owns 32 q rows (2 subtiles of 16).
__global__ __launch_bounds__(256)
void attn_kernel(const u16* __restrict__ Qb, const u16* __restrict__ Kb,
                 const u16* __restrict__ Vt, u16* __restrict__ Ctx) {
  int tid = threadIdx.x, lane = tid & 63, wid = tid >> 6;
  int l15 = lane & 15, g = lane >> 4;
  int qb = (int)gridDim.x - 1 - (int)blockIdx.x;   // heavy q-tiles dispatch first
  int bh = blockIdx.y;
  const u16* Qh = Qb + (size_t)bh * Sq * HDq;
  const u16* Kh = Kb + (size_t)bh * Sq * HDq;
  const u16* Vh = Vt + (size_t)bh * HDq * Sq;

  int base = qb * 128 + wid * 32;   // wave's q rows: [base, base+32)

  // Q fragments: qf[s][h] = Q[base+16s+l15][32h + 8g .. +7]
  short8 qf[2][2];
#pragma unroll
  for (int s = 0; s < 2; ++s)
#pragma unroll
    for (int h = 0; h < 2; ++h)
      qf[s][h] = *reinterpret_cast<const short8*>(&Qh[(size_t)(base + 16 * s + l15) * 64 + 32 * h + 8 * g]);

  f32x4 acc[2][4] = {};
  float m_r[2] = {-INFINITY, -INFINITY};
  float l_r[2] = {0.f, 0.f};
  int nk = (base >> 6) + 1;   // 64-col K blocks covering diag for both subtiles

  for (int kb = 0; kb < nk; ++kb) {
    int k0 = kb * 64;
    // K fragments (A-operand of S^T): kf[j][h] = K[k0+16j+l15][32h + 8g..]
    short8 kf[4][2];
#pragma unroll
    for (int j = 0; j < 4; ++j)
#pragma unroll
      for (int h = 0; h < 2; ++h)
        kf[j][h] = *reinterpret_cast<const short8*>(&Kh[(size_t)(k0 + 16 * j + l15) * 64 + 32 * h + 8 * g]);
    // V fragments (B-operand of PV): vb[n][hf] = Vt[16n+l15][k0 + 32hf + 8g..]  (k-permuted layout)
    short8 vb[4][2];
#pragma unroll
    for (int n = 0; n < 4; ++n)
#pragma unroll
      for (int hf = 0; hf < 2; ++hf)
        vb[n][hf] = *reinterpret_cast<const short8*>(&Vh[(size_t)(16 * n + l15) * 2048 + k0 + 32 * hf + 8 * g]);

#pragma unroll
    for (int s = 0; s < 2; ++s) {
      int q0s = base + 16 * s;
      // S^T tiles: sj[j] holds S[k=k0+16j+4g+r][q=q0s+l15]
      f32x4 sj[4] = {};
#pragma unroll
      for (int j = 0; j < 4; ++j)
#pragma unroll
        for (int h = 0; h < 2; ++h)
          sj[j] = __builtin_amdgcn_mfma_f32_16x16x32_bf16(kf[j][h], qf[s][h], sj[j], 0, 0, 0);

      if (k0 + 63 > q0s) {   // causal mask (only last block(s) near diagonal)
        int q = q0s + l15;
#pragma unroll
        for (int j = 0; j < 4; ++j)
#pragma unroll
          for (int r = 0; r < 4; ++r)
            if (k0 + 16 * j + 4 * g + r > q) sj[j][r] = -1e30f;
      }

      // online softmax over lane's q = q0s + l15 (row spans the 4 g-lanes)
      float mx = sj[0][0];
#pragma unroll
      for (int j = 0; j < 4; ++j)
#pragma unroll
        for (int r = 0; r < 4; ++r) mx = fmaxf(mx, sj[j][r]);
      mx = fmaxf(mx, __shfl_xor(mx, 16));
      mx = fmaxf(mx, __shfl_xor(mx, 32));
      float mn = fmaxf(m_r[s], mx);
      float scn = exp2f(m_r[s] - mn);
      m_r[s] = mn;
      float p[4][4];
      float rs = 0.f;
#pragma unroll
      for (int j = 0; j < 4; ++j)
#pragma unroll
        for (int r = 0; r < 4; ++r) {
          p[j][r] = exp2f(sj[j][r] - mn);
          rs += p[j][r];
        }
      rs += __shfl_xor(rs, 16);
      rs += __shfl_xor(rs, 32);
      l_r[s] = l_r[s] * scn + rs;

      // rescale acc: acc rows are q = q0s + 4g + r -> fetch scn from lane (4g+r)
      float scr[4];
#pragma unroll
      for (int r = 0; r < 4; ++r) scr[r] = __shfl(scn, 4 * g + r);
#pragma unroll
      for (int n = 0; n < 4; ++n)
#pragma unroll
        for (int r = 0; r < 4; ++r) acc[s][n][r] *= scr[r];

      // pack P into PV A-fragments (in-register, k' permuted to match Vt)
      short8 pa0, pa1;
#pragma unroll
      for (int r = 0; r < 4; ++r) {
        pa0[r]     = (short)f2bf(p[0][r]);
        pa0[4 + r] = (short)f2bf(p[2][r]);
        pa1[r]     = (short)f2bf(p[1][r]);
        pa1[4 + r] = (short)f2bf(p[3][r]);
      }
#pragma unroll
      for (int n = 0; n < 4; ++n) {
        acc[s][n] = __builtin_amdgcn_mfma_f32_16x16x32_bf16(pa0, vb[n][0], acc[s][n], 0, 0, 0);
        acc[s][n] = __builtin_amdgcn_mfma_f32_16x16x32_bf16(pa1, vb[n][1], acc[s][n], 0, 0, 0);
      }
    }
  }

  // epilogue: acc rows q = base + 16s + 4g + r, col d = 16n + l15
  int b = bh >> 4, h = bh & 15;
#pragma unroll
  for (int s = 0; s < 2; ++s) {
    float lf[4];
#pragma unroll
    for (int r = 0; r < 4; ++r) lf[r] = __shfl(l_r[s], 4 * g + r);
#pragma unroll
    for (int r = 0; r < 4; ++r) {
      float inv = 1.0f / lf[r];
      int row = base + 16 * s + 4 * g + r;
      size_t obase = ((size_t)(b * Sq + row)) * Dq + h * 64;
#pragma unroll
      for (int n = 0; n < 4; ++n)
        Ctx[obase + 16 * n + l15] = f2bf(acc[s][n][r] * inv);
    }
  }
}

extern "C" void kernel_launch(void* const* d_in, const int* in_sizes, int n_in,
                              void* d_out, int out_size, void* d_ws, size_t ws_size,
                              hipStream_t stream) {
  const float* X  = (const float*)d_in[0];   // [B,S,D] fp32
  const float* Wa = (const float*)d_in[1];   // [D,3D]
  const float* Ba = (const float*)d_in[2];   // [3D]
  const float* Wp = (const float*)d_in[3];   // [D,D]
  const float* Bp = (const float*)d_in[4];   // [D]
  float* Out = (float*)d_out;                // [B,S,D] fp32

  u16* ws  = (u16*)d_ws;
  u16* Xb  = ws;                                 // 8192*1024
  u16* WaT = Xb  + (size_t)BSq * Dq;             // 3072*1024
  u16* WpT = WaT + (size_t)3 * Dq * Dq;          // 1024*1024
  u16* Qb  = WpT + (size_t)Dq * Dq;              // 64*2048*64
  u16* Kb  = Qb  + (size_t)Bq * Hq * Sq * HDq;
  u16* Vt  = Kb  + (size_t)Bq * Hq * Sq * HDq;
  u16* Ctx = Vt  + (size_t)Bq * Hq * Sq * HDq;   // 8192*1024

  // 1) convert X to bf16
  cvt_kernel<<<(BSq * Dq / 4 + 255) / 256, 256, 0, stream>>>(X, Xb, BSq * Dq / 4);
  // 2) transpose+convert weights: W[K][N] -> WT[N][K] bf16
  transpose_cvt<<<dim3(3 * Dq / 32, Dq / 32), dim3(32, 8), 0, stream>>>(Wa, WaT, Dq, 3 * Dq);
  transpose_cvt<<<dim3(Dq / 32, Dq / 32), dim3(32, 8), 0, stream>>>(Wp, WpT, Dq, Dq);
  // 3) QKV GEMM (M=8192, N=3072, K=1024) with Q/K/V scatter epilogue
  gemm_bt<0><<<dim3(3 * Dq / 128, BSq / 128), 256, 0, stream>>>(Xb, WaT, Ba, Qb, Kb, Vt, nullptr, Dq);
  // 4) causal flash attention -> Ctx [B,S,H*HD] bf16
  attn_kernel<<<dim3(Sq / 128, Bq * Hq), 256, 0, stream>>>(Qb, Kb, Vt, Ctx);
  // 5) output projection (M=8192, N=1024, K=1024) -> fp32 out
  gemm_bt<1><<<dim3(Dq / 128, BSq / 128), 256, 0, stream>>>(Ctx, WpT, Bp, nullptr, nullptr, nullptr, Out, Dq);
}

// Round 3
// 266.124 us; speedup vs baseline: 2.1947x; 1.3791x over previous
//
#include <hip/hip_runtime.h>

typedef unsigned short u16;
typedef __attribute__((ext_vector_type(8))) short short8;
typedef __attribute__((ext_vector_type(4))) float f32x4;
typedef __attribute__((ext_vector_type(4))) unsigned u32x4;

// Problem dims
#define Bq 4
#define Sq 2048
#define Dq 1024
#define Hq 16
#define HDq 64
#define BSq 8192   // B*S
#define NT 16      // q-tiles of 128

// Q pre-scale: 1/sqrt(64) * log2(e)  (softmax done in exp2 domain)
#define QSCALE 0.18033688011112042f

__device__ __forceinline__ u16 f2bf(float f) {
  unsigned u = __builtin_bit_cast(unsigned, f);
  unsigned r = u + 0x7fffu + ((u >> 16) & 1u);
  return (u16)(r >> 16);
}

// pack two floats -> (bf16(a) | bf16(b)<<16), round-half-up via +0x8000 then v_perm
__device__ __forceinline__ unsigned pk2(float a, float b) {
  unsigned ua = __builtin_bit_cast(unsigned, a) + 0x8000u;
  unsigned ub = __builtin_bit_cast(unsigned, b) + 0x8000u;
  return __builtin_amdgcn_perm(ub, ua, 0x07060302u);
}

// async global->LDS, 16B per lane (dest = wave-uniform base + lane*16)
__device__ __forceinline__ void gl_lds16(const u16* g, u16* l) {
  __builtin_amdgcn_global_load_lds((const __attribute__((address_space(1))) unsigned int*)g,
                                   (__attribute__((address_space(3))) unsigned int*)l, 16, 0, 0);
}

// k-permutation for V^T storage: kk = 16j + 4g + r  ->  k' matching PV A-frag packing
__device__ __forceinline__ int kperm(int kk) {
  return ((kk & 0x10) << 1) | ((kk & 0x0C) << 1) | ((kk & 0x20) >> 3) | (kk & 3);
}

// ---------------- fp32 -> bf16 convert (float4 vectorized) ----------------
__global__ void cvt_kernel(const float* __restrict__ in, u16* __restrict__ out, int n4) {
  int i = blockIdx.x * blockDim.x + threadIdx.x;
  if (i >= n4) return;
  float4 v = reinterpret_cast<const float4*>(in)[i];
  ushort4 o;
  o.x = f2bf(v.x); o.y = f2bf(v.y); o.z = f2bf(v.z); o.w = f2bf(v.w);
  reinterpret_cast<ushort4*>(out)[i] = o;
}

// ---------------- transpose + convert: fp32 [R][C] -> bf16 [C][R] ----------------
__global__ void transpose_cvt(const float* __restrict__ in, u16* __restrict__ out, int R, int C) {
  __shared__ float tile[32][33];
  int c0 = blockIdx.x * 32, r0 = blockIdx.y * 32;
  for (int i = threadIdx.y; i < 32; i += 8)
    tile[i][threadIdx.x] = in[(size_t)(r0 + i) * C + c0 + threadIdx.x];
  __syncthreads();
  for (int i = threadIdx.y; i < 32; i += 8)
    out[(size_t)(c0 + i) * R + r0 + threadIdx.x] = f2bf(tile[threadIdx.x][i]);
}

// ---------------- bf16 GEMM: C[M,N] = A[M,K] * Bt[N,K]^T  (+bias) ----------------
// global_load_lds (16B) staging, m97 2-barrier structure.
// EPI 0: QKV epilogue; EPI 1: proj epilogue -> fp32 Out
template<int EPI>
__global__ __launch_bounds__(256)
void gemm_bt(const u16* __restrict__ A, const u16* __restrict__ Bt,
             const float* __restrict__ bias,
             u16* __restrict__ Qb, u16* __restrict__ Kb, u16* __restrict__ Vt,
             float* __restrict__ Out, int Kdim) {
  __shared__ __align__(16) u16 As[128 * 32];
  __shared__ __align__(16) u16 Bs[128 * 32];
  int tid = threadIdx.x;
  int lane = tid & 63, wid = tid >> 6;
  int wr = wid >> 1, wc = wid & 1;       // 2x2 waves; each computes 64x64
  int m0 = blockIdx.y * 128, n0 = blockIdx.x * 128;
  int l15 = lane & 15, g = lane >> 4;
  f32x4 acc[4][4] = {};
  int srow = tid >> 2, scol = (tid & 3) * 8;

  for (int k0 = 0; k0 < Kdim; k0 += 32) {
    __syncthreads();   // previous iteration's LDS reads complete
    gl_lds16(&A[(size_t)(m0 + srow) * Kdim + k0 + scol],       As + wid * 512);
    gl_lds16(&A[(size_t)(m0 + 64 + srow) * Kdim + k0 + scol],  As + 2048 + wid * 512);
    gl_lds16(&Bt[(size_t)(n0 + srow) * Kdim + k0 + scol],      Bs + wid * 512);
    gl_lds16(&Bt[(size_t)(n0 + 64 + srow) * Kdim + k0 + scol], Bs + 2048 + wid * 512);
    __syncthreads();   // vmcnt drained -> tiles visible
    short8 af[4], bfr[4];
#pragma unroll
    for (int m = 0; m < 4; ++m)
      af[m] = *reinterpret_cast<const short8*>(&As[(wr * 64 + m * 16 + l15) * 32 + g * 8]);
#pragma unroll
    for (int n = 0; n < 4; ++n)
      bfr[n] = *reinterpret_cast<const short8*>(&Bs[(wc * 64 + n * 16 + l15) * 32 + g * 8]);
#pragma unroll
    for (int m = 0; m < 4; ++m)
#pragma unroll
      for (int n = 0; n < 4; ++n)
        acc[m][n] = __builtin_amdgcn_mfma_f32_16x16x32_bf16(af[m], bfr[n], acc[m][n], 0, 0, 0);
  }

#pragma unroll
  for (int m = 0; m < 4; ++m) {
#pragma unroll
    for (int n = 0; n < 4; ++n) {
      int gcol = n0 + wc * 64 + n * 16 + l15;
      float bv = bias[gcol];
#pragma unroll
      for (int r = 0; r < 4; ++r) {
        int grow = m0 + wr * 64 + m * 16 + g * 4 + r;
        float v = acc[m][n][r] + bv;
        if (EPI == 0) {
          int b = grow >> 11, s = grow & 2047;
          if (gcol < 1024) {
            int h = gcol >> 6, d = gcol & 63;
            Qb[(((size_t)(b * 16 + h) * 2048 + s) << 6) + d] = f2bf(v * QSCALE);
          } else if (gcol < 2048) {
            int c = gcol - 1024, h = c >> 6, d = c & 63;
            Kb[(((size_t)(b * 16 + h) * 2048 + s) << 6) + d] = f2bf(v);
          } else {
            int c = gcol - 2048, h = c >> 6, d = c & 63;
            Vt[((size_t)(b * 16 + h) * 64 + d) * 2048 + (s & ~63) + kperm(s & 63)] = f2bf(v);
          }
        } else {
          Out[(size_t)grow * 1024 + gcol] = v;
        }
      }
    }
  }
}

// ---------------- flash attention (causal), swapped-QK^T, all-register P ----------------
// grid: (8 tile-pairs, B*H). Block handles q-tiles (15-bx) then (bx): equal work.
// 4 waves; wave owns 32 q rows (2 subtiles of 16). Single-buffer pipelined loads.
__global__ __launch_bounds__(256, 2)
void attn_kernel(const u16* __restrict__ Qb, const u16* __restrict__ Kb,
                 const u16* __restrict__ Vt, u16* __restrict__ Ctx) {
  int tid = threadIdx.x, lane = tid & 63, wid = tid >> 6;
  int l15 = lane & 15, g = lane >> 4;
  int bh = blockIdx.y;
  const u16* Qh = Qb + (size_t)bh * Sq * HDq;
  const u16* Kh = Kb + (size_t)bh * Sq * HDq;
  const u16* Vh = Vt + (size_t)bh * HDq * Sq;
  const u16* kp = Kh + l15 * 64 + g * 8;           // K frag base (lane-resolved)
  const u16* vp = Vh + (size_t)l15 * Sq + g * 8;   // V frag base
  int b = bh >> 4, h = bh & 15;

#pragma unroll 1
  for (int t = 0; t < 2; ++t) {
    int qb = t == 0 ? (NT - 1 - (int)blockIdx.x) : (int)blockIdx.x;  // heavy tile first
    int base = qb * 128 + wid * 32;   // wave's q rows: [base, base+32)

    short8 qf[2][2];
#pragma unroll
    for (int s = 0; s < 2; ++s)
#pragma unroll
      for (int hh = 0; hh < 2; ++hh)
        qf[s][hh] = *reinterpret_cast<const short8*>(&Qh[(size_t)(base + 16 * s + l15) * 64 + 32 * hh + 8 * g]);

    f32x4 acc[2][4] = {};
    float m_r[2] = {-INFINITY, -INFINITY};
    float l_r[2] = {0.f, 0.f};
    int nk = (base >> 6) + 1;

    // prologue: K frags for kb=0
    short8 kf[4][2];
#pragma unroll
    for (int j = 0; j < 4; ++j)
#pragma unroll
      for (int hh = 0; hh < 2; ++hh)
        kf[j][hh] = *reinterpret_cast<const short8*>(&kp[(size_t)(16 * j) * 64 + 32 * hh]);

#pragma unroll 1
    for (int kb = 0; kb < nk; ++kb) {
      int k0 = kb * 64;
      // V loads for this iter (consumed at PV, ~600cy later)
      short8 vb[4][2];
#pragma unroll
      for (int n = 0; n < 4; ++n)
#pragma unroll
        for (int hf = 0; hf < 2; ++hf)
          vb[n][hf] = *reinterpret_cast<const short8*>(&vp[(size_t)(16 * n) * Sq + k0 + 32 * hf]);

      // QK^T both subtiles (consumes kf)
      f32x4 sj[2][4];
#pragma unroll
      for (int s = 0; s < 2; ++s)
#pragma unroll
        for (int j = 0; j < 4; ++j) {
          f32x4 z = {};
          z = __builtin_amdgcn_mfma_f32_16x16x32_bf16(kf[j][0], qf[s][0], z, 0, 0, 0);
          z = __builtin_amdgcn_mfma_f32_16x16x32_bf16(kf[j][1], qf[s][1], z, 0, 0, 0);
          sj[s][j] = z;
        }

      // refill kf for next iter (kf regs free after QK^T issue)
      if (kb + 1 < nk) {
#pragma unroll
        for (int j = 0; j < 4; ++j)
#pragma unroll
          for (int hh = 0; hh < 2; ++hh)
            kf[j][hh] = *reinterpret_cast<const short8*>(&kp[(size_t)(k0 + 64 + 16 * j) * 64 + 32 * hh]);
      }

#pragma unroll
      for (int s = 0; s < 2; ++s) {
        int q0s = base + 16 * s;
        if (k0 + 63 > q0s) {   // causal mask near diagonal
          int q = q0s + l15;
#pragma unroll
          for (int j = 0; j < 4; ++j)
#pragma unroll
            for (int r = 0; r < 4; ++r)
              if (k0 + 16 * j + 4 * g + r > q) sj[s][j][r] = -1e30f;
        }

        // row max (lane's q = q0s + l15; row spans g-groups)
        float mx = sj[s][0][0];
#pragma unroll
        for (int j = 0; j < 4; ++j)
#pragma unroll
          for (int r = 0; r < 4; ++r) mx = fmaxf(mx, sj[s][j][r]);
        mx = fmaxf(mx, __shfl_xor(mx, 16));
        mx = fmaxf(mx, __shfl_xor(mx, 32));

        float mn = m_r[s];
        if (!__all(mx - mn <= 8.0f)) {   // defer-max: rescale only on real growth
          float mnew = fmaxf(mn, mx);
          float scn = exp2f(mn - mnew);
          float scr[4];
#pragma unroll
          for (int r = 0; r < 4; ++r) scr[r] = __shfl(scn, 4 * g + r);
#pragma unroll
          for (int n = 0; n < 4; ++n)
#pragma unroll
            for (int r = 0; r < 4; ++r) acc[s][n][r] *= scr[r];
          l_r[s] *= scn;
          m_r[s] = mnew;
          mn = mnew;
        }

        float p[4][4];
        float rs = 0.f;
#pragma unroll
        for (int j = 0; j < 4; ++j)
#pragma unroll
          for (int r = 0; r < 4; ++r) {
            p[j][r] = exp2f(sj[s][j][r] - mn);
            rs += p[j][r];
          }
        rs += __shfl_xor(rs, 16);
        rs += __shfl_xor(rs, 32);
        l_r[s] += rs;

        // pack P -> PV A-frags (v_perm pair pack, k' order matches Vt)
        u32x4 w0, w1;
        w0[0] = pk2(p[0][0], p[0][1]); w0[1] = pk2(p[0][2], p[0][3]);
        w0[2] = pk2(p[2][0], p[2][1]); w0[3] = pk2(p[2][2], p[2][3]);
        w1[0] = pk2(p[1][0], p[1][1]); w1[1] = pk2(p[1][2], p[1][3]);
        w1[2] = pk2(p[3][0], p[3][1]); w1[3] = pk2(p[3][2], p[3][3]);
        short8 pa0 = __builtin_bit_cast(short8, w0);
        short8 pa1 = __builtin_bit_cast(short8, w1);
#pragma unroll
        for (int n = 0; n < 4; ++n) {
          acc[s][n] = __builtin_amdgcn_mfma_f32_16x16x32_bf16(pa0, vb[n][0], acc[s][n], 0, 0, 0);
          acc[s][n] = __builtin_amdgcn_mfma_f32_16x16x32_bf16(pa1, vb[n][1], acc[s][n], 0, 0, 0);
        }
      }
    }

    // epilogue: rows q = base + 16s + 4g + r, col d = 16n + l15
#pragma unroll
    for (int s = 0; s < 2; ++s) {
      float lf[4];
#pragma unroll
      for (int r = 0; r < 4; ++r) lf[r] = __shfl(l_r[s], 4 * g + r);
#pragma unroll
      for (int r = 0; r < 4; ++r) {
        float inv = 1.0f / lf[r];
        int row = base + 16 * s + 4 * g + r;
        size_t obase = ((size_t)(b * Sq + row)) * Dq + h * 64;
#pragma unroll
        for (int n = 0; n < 4; ++n)
          Ctx[obase + 16 * n + l15] = f2bf(acc[s][n][r] * inv);
      }
    }
  }
}

extern "C" void kernel_launch(void* const* d_in, const int* in_sizes, int n_in,
                              void* d_out, int out_size, void* d_ws, size_t ws_size,
                              hipStream_t stream) {
  const float* X  = (const float*)d_in[0];   // [B,S,D] fp32
  const float* Wa = (const float*)d_in[1];   // [D,3D]
  const float* Ba = (const float*)d_in[2];   // [3D]
  const float* Wp = (const float*)d_in[3];   // [D,D]
  const float* Bp = (const float*)d_in[4];   // [D]
  float* Out = (float*)d_out;                // [B,S,D] fp32

  u16* ws  = (u16*)d_ws;
  u16* Xb  = ws;                                 // 8192*1024
  u16* WaT = Xb  + (size_t)BSq * Dq;             // 3072*1024
  u16* WpT = WaT + (size_t)3 * Dq * Dq;          // 1024*1024
  u16* Qb  = WpT + (size_t)Dq * Dq;              // 64*2048*64
  u16* Kb  = Qb  + (size_t)Bq * Hq * Sq * HDq;
  u16* Vt  = Kb  + (size_t)Bq * Hq * Sq * HDq;
  u16* Ctx = Vt  + (size_t)Bq * Hq * Sq * HDq;   // 8192*1024

  // 1) convert X to bf16
  cvt_kernel<<<(BSq * Dq / 4 + 255) / 256, 256, 0, stream>>>(X, Xb, BSq * Dq / 4);
  // 2) transpose+convert weights: W[K][N] -> WT[N][K] bf16
  transpose_cvt<<<dim3(3 * Dq / 32, Dq / 32), dim3(32, 8), 0, stream>>>(Wa, WaT, Dq, 3 * Dq);
  transpose_cvt<<<dim3(Dq / 32, Dq / 32), dim3(32, 8), 0, stream>>>(Wp, WpT, Dq, Dq);
  // 3) QKV GEMM (M=8192, N=3072, K=1024) with Q/K/V scatter epilogue
  gemm_bt<0><<<dim3(3 * Dq / 128, BSq / 128), 256, 0, stream>>>(Xb, WaT, Ba, Qb, Kb, Vt, nullptr, Dq);
  // 4) causal flash attention -> Ctx [B,S,H*HD] bf16 (paired q-tiles, equal work)
  attn_kernel<<<dim3(NT / 2, Bq * Hq), 256, 0, stream>>>(Qb, Kb, Vt, Ctx);
  // 5) output projection (M=8192, N=1024, K=1024) -> fp32 out
  gemm_bt<1><<<dim3(Dq / 128, BSq / 128), 256, 0, stream>>>(Ctx, WpT, Bp, nullptr, nullptr, nullptr, Out, Dq);
}